// Round 4
// baseline (148.379 us; speedup 1.0000x reference)
//
#include <hip/hip_runtime.h>
#include <math.h>

typedef _Float16 f16;
typedef _Float16 f16x8 __attribute__((ext_vector_type(8)));
typedef float f32x4 __attribute__((ext_vector_type(4)));
typedef float f32x16 __attribute__((ext_vector_type(16)));

#define BB 4
#define CC 256
#define CI 128
#define NN 12544
#define MM 1568
#define TP 8
#define HP 14
#define WP 14

// workspace byte offsets (all 16B aligned)
#define OFF_W3T 0u
#define OFF_WWH 196608u
#define OFF_B3  262144u
#define OFF_SC  263168u
#define OFF_OFB 264192u
#define OFF_XT  265216u
#define OFF_TPG (OFF_XT + 25690112u)
#define OFF_PHI (OFF_TPG + 38535168u)
#define OFF_G   (OFF_PHI + 1605632u)
#define OFF_Y   (OFF_G + 1605632u)
#define WS_NEED (OFF_Y + 12845056u)

static __device__ __forceinline__ f32x4 mfma16(f16x8 a, f16x8 b, f32x4 c) {
    return __builtin_amdgcn_mfma_f32_16x16x32_f16(a, b, c, 0, 0, 0);
}
static __device__ __forceinline__ f32x16 mfma32(f16x8 a, f16x8 b, f32x16 c) {
    return __builtin_amdgcn_mfma_f32_32x32x16_f16(a, b, c, 0, 0, 0);
}
static __device__ __forceinline__ unsigned pkrtz(float a, float b) {
    auto h = __builtin_amdgcn_cvt_pkrtz(a, b);
    return __builtin_bit_cast(unsigned, h);
}
// async global->LDS DMA, 16B per lane; LDS dest = wave-uniform base + lane*16 (linear)
static __device__ __forceinline__ void gload16(const f16* g, f16* l) {
    __builtin_amdgcn_global_load_lds((const __attribute__((address_space(1))) void*)g,
                                     (__attribute__((address_space(3))) void*)l, 16, 0, 0);
}

// ---------------- K0a: weight prep ----------------
__global__ __launch_bounds__(256) void k_prep(
    const float* __restrict__ wg, const float* __restrict__ bg,
    const float* __restrict__ wth, const float* __restrict__ bth_,
    const float* __restrict__ wph, const float* __restrict__ bph,
    const float* __restrict__ wW, const float* __restrict__ bW,
    const float* __restrict__ gam, const float* __restrict__ bet,
    const float* __restrict__ mean, const float* __restrict__ var,
    f16* __restrict__ w3t, f16* __restrict__ wWh, f16* __restrict__ b3,
    float* __restrict__ sc, float* __restrict__ ofb) {
    int r = blockIdx.x;          // 0..383
    int c = threadIdx.x;         // 0..255
    const float* src = (r < 128) ? (wth + (size_t)r * CC)
                     : (r < 256) ? (wph + (size_t)(r - 128) * CC)
                                 : (wg + (size_t)(r - 256) * CC);
    w3t[(size_t)r * CC + c] = (f16)src[c];
    if (c == 0) {
        float bv = (r < 128) ? bth_[r] : (r < 256) ? bph[r - 128] : bg[r - 256];
        b3[r] = (f16)bv;
    }
    if (r < 256) {
        if (c < 128) wWh[(size_t)r * CI + c] = (f16)wW[(size_t)r * CI + c];
        if (c == 0) {
            float s = gam[r] * rsqrtf(var[r] + 1e-5f);
            sc[r] = s;
            ofb[r] = (bW[r] - mean[r]) * s + bet[r];
        }
    }
}

// ---------------- K0b: x (c,n) f32 -> xT (n,c) fp16 ----------------
__global__ __launch_bounds__(256) void k_xt(const float* __restrict__ x, f16* __restrict__ xT) {
    int bid = blockIdx.x;                 // BB*196*4
    int b = bid / (196 * 4); int rem = bid % (196 * 4);
    int nt = rem / 4, ct = rem % 4;
    int n0 = nt * 64, c0 = ct * 64;
    __shared__ float tile[64][65];
    const float* xb = x + (size_t)b * CC * NN;
    for (int p = 0; p < 16; ++p) {
        int idx = p * 256 + threadIdx.x;
        int i = idx >> 6, j = idx & 63;   // i=c-local, j=n-local
        tile[i][j] = xb[(size_t)(c0 + i) * NN + n0 + j];
    }
    __syncthreads();
    f16* xTb = xT + (size_t)b * NN * CC;
    for (int p = 0; p < 16; ++p) {
        int idx = p * 256 + threadIdx.x;
        int n = idx >> 6, c = idx & 63;
        xTb[(size_t)(n0 + n) * CC + c0 + c] = (f16)tile[c][n];
    }
}

// ---------------- K1: fused conv GEMM  tpg[n][0:384] = xT(n,:) @ w3t^T + b3 ----------------
// DMA-staged (gload_lds, pre-swizzled source), double-buffered, 1 barrier/K-step.
__global__ __launch_bounds__(256) void k_conv(const f16* __restrict__ xT, const f16* __restrict__ w3t,
                                              const f16* __restrict__ b3, f16* __restrict__ tpg) {
    int bid = blockIdx.x;                 // BB*98*3
    int b = bid / (98 * 3); int rem = bid % (98 * 3);
    int nt = rem / 3, ct = rem % 3;
    int n0 = nt * 128, co0 = ct * 128;
    __shared__ f16 SB[2][16384];          // per buf: As 8192 halves [128n][64k], Bs 8192 [128co][64k]
    const f16* xb = xT + (size_t)b * NN * CC + (size_t)n0 * CC;
    const f16* wb = w3t + (size_t)co0 * CC;
    int tid = threadIdx.x;
    int wv = tid >> 6, ln = tid & 63;
    int wr = (wv & 1) * 64, wc = (wv >> 1) * 64;
    // staging geometry: 16 DMA instrs per matrix, wave wv owns [wv*4, wv*4+4)
    int k0 = wv * 4;
    const f16* sA[4]; const f16* sB_[4]; int dA[4], dB[4];
    #pragma unroll
    for (int i = 0; i < 4; ++i) {
        int s16 = (k0 + i) * 64 + ln;     // 16B-slot index in [0,1024)
        int row = s16 >> 3, sl = s16 & 7; // 8 slots per 64-half row
        sA[i] = xb + (size_t)row * CC + ((sl ^ (row & 7)) << 3);
        sB_[i] = wb + (size_t)row * CC + ((sl ^ (row & 7)) << 3);
        dA[i] = (k0 + i) * 512;
        dB[i] = 8192 + (k0 + i) * 512;
    }
    f32x4 acc[4][4];
    #pragma unroll
    for (int i = 0; i < 4; ++i)
        #pragma unroll
        for (int j = 0; j < 4; ++j)
            #pragma unroll
            for (int r = 0; r < 4; ++r) acc[i][j][r] = 0.f;
    // prologue
    #pragma unroll
    for (int i = 0; i < 4; ++i) { gload16(sA[i], SB[0] + dA[i]); gload16(sB_[i], SB[0] + dB[i]); }
    __syncthreads();
    for (int ks = 0; ks < 4; ++ks) {
        if (ks < 3) {
            f16* nb = SB[(ks + 1) & 1];
            #pragma unroll
            for (int i = 0; i < 4; ++i) {
                gload16(sA[i] + (ks + 1) * 64, nb + dA[i]);
                gload16(sB_[i] + (ks + 1) * 64, nb + dB[i]);
            }
        }
        const f16* As = SB[ks & 1];
        const f16* Bs = As + 8192;
        #pragma unroll
        for (int kc = 0; kc < 2; ++kc) {
            int klo = kc * 32 + ((ln >> 4) * 8);
            f16x8 af[4], bf[4];
            #pragma unroll
            for (int i = 0; i < 4; ++i) {
                int rn = wr + i * 16 + (ln & 15);
                af[i] = *(const f16x8*)(As + rn * 64 + (klo ^ ((rn & 7) << 3)));
                int rc = wc + i * 16 + (ln & 15);
                bf[i] = *(const f16x8*)(Bs + rc * 64 + (klo ^ ((rc & 7) << 3)));
            }
            #pragma unroll
            for (int i = 0; i < 4; ++i)
                #pragma unroll
                for (int j = 0; j < 4; ++j)
                    acc[i][j] = mfma16(af[i], bf[j], acc[i][j]);
        }
        __syncthreads();
    }
    f16* ob = tpg + (size_t)b * NN * 384 + (size_t)n0 * 384 + co0;
    #pragma unroll
    for (int j = 0; j < 4; ++j) {
        float bias = (float)b3[co0 + wc + j * 16 + (ln & 15)];
        #pragma unroll
        for (int i = 0; i < 4; ++i)
            #pragma unroll
            for (int r = 0; r < 4; ++r) {
                int n = wr + i * 16 + (ln >> 4) * 4 + r;
                int co = wc + j * 16 + (ln & 15);
                ob[(size_t)n * 384 + co] = (f16)(acc[i][j][r] + bias);
            }
    }
}

// ---------------- K2: maxpool -> phi (m,ci), g (ci,m) ----------------
__global__ __launch_bounds__(256) void k_pool(const f16* __restrict__ tpg,
                                              f16* __restrict__ phi, f16* __restrict__ gx) {
    int bid = blockIdx.x;                 // BB*TP*HP
    int b = bid / (TP * HP); int rem = bid % (TP * HP);
    int tp = rem / HP, hp = rem % HP;
    const f16* base = tpg + (size_t)b * NN * 384;
    for (int idx = threadIdx.x; idx < WP * 128; idx += 256) {
        int wp = idx >> 7, ci = idx & 127;
        f16 mp = (f16)(-60000.0f), mg = (f16)(-60000.0f);
        for (int dt = 0; dt < 2; ++dt)
            for (int dh = 0; dh < 2; ++dh)
                for (int dw = 0; dw < 2; ++dw) {
                    int n = (2 * tp + dt) * 784 + (2 * hp + dh) * 28 + (2 * wp + dw);
                    f16 vp = base[(size_t)n * 384 + 128 + ci];
                    f16 vg = base[(size_t)n * 384 + 256 + ci];
                    mp = vp > mp ? vp : mp;
                    mg = vg > mg ? vg : mg;
                }
        int m = tp * 196 + hp * 14 + wp;
        phi[(size_t)b * MM * CI + (size_t)m * CI + ci] = mp;
        gx[(size_t)b * CI * MM + (size_t)ci * MM + m] = mg;
    }
}

// ---------------- K3: swapped flash attention (32x32 MFMA) ----------------
// QK swapped: D[key][q] = phi_chunk . theta^T ; PV swapped: D[ci][q] = g^T . P.
// LDS buf layout (per 16KB half): Bp [64 keys][128 ci] slot-swizzled sl^=(row&15);
//                                 Bg [128 ci][64 keys] slot-swizzled sl^=(row&7).
// Staged via gload_lds DMA: LINEAR LDS dest + inverse-swizzled GLOBAL source (same XOR).

template<int KF>   // keyfrags of 32 keys; chunk = KF*32 keys
__device__ __forceinline__ void attn_chunk(const f16* __restrict__ Bp, const f16* __restrict__ Bg,
                                           const f16x8* bth, f32x16* yv,
                                           float& mrun, float& lrun, int lq, int hi) {
    f32x16 qk[KF];
    __builtin_amdgcn_s_setprio(1);
    #pragma unroll
    for (int kf = 0; kf < KF; ++kf) {
        #pragma unroll
        for (int r = 0; r < 16; ++r) qk[kf][r] = 0.f;
        int row = kf * 32 + lq;
        const f16* rp = Bp + row * 128;
        int sw = (row & 15) << 3;
        #pragma unroll
        for (int ks = 0; ks < 8; ++ks)
            qk[kf] = mfma32(*(const f16x8*)(rp + ((ks * 16 + hi * 8) ^ sw)), bth[ks], qk[kf]);
    }
    __builtin_amdgcn_s_setprio(0);
    // chunk max for this lane's q (own halves + partner half via shfl)
    float t[8];
    #pragma unroll
    for (int i = 0; i < 8; ++i) {
        t[i] = fmaxf(qk[0][i], qk[0][i + 8]);
        if (KF == 2) t[i] = fmaxf(t[i], fmaxf(qk[KF - 1][i], qk[KF - 1][i + 8]));
    }
    #pragma unroll
    for (int s = 4; s >= 1; s >>= 1)
        #pragma unroll
        for (int i = 0; i < s; ++i) t[i] = fmaxf(t[i], t[i + s]);
    float mx = fmaxf(t[0], __shfl_xor(t[0], 32));
    // defer-max (T13): only rescale when max grew by > 8
    if (__any(mx > mrun + 8.f)) {
        float mnew = fmaxf(mrun, mx);
        float scl = __expf(mrun - mnew);
        lrun *= scl;
        #pragma unroll
        for (int c = 0; c < 4; ++c)
            #pragma unroll
            for (int r = 0; r < 16; ++r) yv[c][r] *= scl;
        mrun = mnew;
    }
    float ps = 0.f;
    #pragma unroll
    for (int kf = 0; kf < KF; ++kf)
        #pragma unroll
        for (int r = 0; r < 16; ++r) {
            float p = __expf(qk[kf][r] - mrun);
            qk[kf][r] = p;
            ps += p;
        }
    ps += __shfl_xor(ps, 32);
    lrun += ps;
    // pack P to PV B-frags (16-key slices), cross-half exchange via shfl_xor(32)
    #pragma unroll
    for (int s = 0; s < 2 * KF; ++s) {
        const int kf = s >> 1;
        const int base = (s & 1) * 8;
        unsigned A0 = pkrtz(qk[kf][base + 0], qk[kf][base + 1]);
        unsigned A1 = pkrtz(qk[kf][base + 2], qk[kf][base + 3]);
        unsigned B0 = pkrtz(qk[kf][base + 4], qk[kf][base + 5]);
        unsigned B1 = pkrtz(qk[kf][base + 6], qk[kf][base + 7]);
        unsigned g0 = (unsigned)__shfl_xor((int)(hi ? A0 : B0), 32);
        unsigned g1 = (unsigned)__shfl_xor((int)(hi ? A1 : B1), 32);
        union { unsigned u[4]; f16x8 v; } fr;
        fr.u[0] = hi ? g0 : A0;
        fr.u[1] = hi ? g1 : A1;
        fr.u[2] = hi ? B0 : g0;
        fr.u[3] = hi ? B1 : g1;
        __builtin_amdgcn_s_setprio(1);
        #pragma unroll
        for (int c = 0; c < 4; ++c) {
            int row = c * 32 + lq;
            f16x8 gfr = *(const f16x8*)(Bg + row * 64 + ((s * 16 + hi * 8) ^ ((row & 7) << 3)));
            yv[c] = mfma32(gfr, fr.v, yv[c]);
        }
        __builtin_amdgcn_s_setprio(0);
    }
}

__global__ __launch_bounds__(256, 2) void k_attn(const f16* __restrict__ tpg, const f16* __restrict__ phi,
                                                 const f16* __restrict__ gx, f16* __restrict__ y) {
    int bid = blockIdx.x;                 // BB*98
    int b = bid / 98; int nt = bid % 98;
    int n0 = nt * 128;
    __shared__ f16 SB[2][16384];          // dbuf: per buf Bp 8192 + Bg 8192 halves (64KB total)
    int tid = threadIdx.x;
    int wv = tid >> 6, ln = tid & 63, hi = ln >> 5, lq = ln & 31;
    // theta B-frags for this lane's q = n0 + wv*32 + lq (kept in regs)
    f16x8 bth[8];
    {
        const f16* rowp = tpg + ((size_t)b * NN + n0 + wv * 32 + lq) * 384;
        #pragma unroll
        for (int ks = 0; ks < 8; ++ks)
            bth[ks] = *(const f16x8*)(rowp + ks * 16 + hi * 8);
    }
    f32x16 yv[4];
    #pragma unroll
    for (int c = 0; c < 4; ++c)
        #pragma unroll
        for (int r = 0; r < 16; ++r) yv[c][r] = 0.f;
    float mrun = -1e30f, lrun = 0.f;
    const f16* phib = phi + (size_t)b * MM * CI;
    const f16* gb = gx + (size_t)b * CI * MM;
    // staging geometry: Bp = 16 DMA instrs, Bg = 16; wave wv owns [wv*4, wv*4+4) of each
    int k0 = wv * 4;
    const f16* sP[4]; const f16* sG[4]; int dP[4], dG[4];
    #pragma unroll
    for (int i = 0; i < 4; ++i) {
        int s16 = (k0 + i) * 64 + ln;       // slot in [0,1024)
        int row = s16 >> 4, sl = s16 & 15;  // Bp: 16 slots per 128-half row
        sP[i] = phib + (size_t)row * CI + ((sl ^ (row & 15)) << 3);
        dP[i] = (k0 + i) * 512;
        int row2 = s16 >> 3, sl2 = s16 & 7; // Bg: 8 slots per 64-half row
        sG[i] = gb + (size_t)row2 * MM + ((sl2 ^ (row2 & 7)) << 3);
        dG[i] = 8192 + (k0 + i) * 512;
    }
    // prologue: chunk 0 -> buf0
    #pragma unroll
    for (int i = 0; i < 4; ++i) { gload16(sP[i], SB[0] + dP[i]); gload16(sG[i], SB[0] + dG[i]); }
    __syncthreads();
    for (int t = 0; t < 24; ++t) {
        f16* nb = SB[(t + 1) & 1];
        if (t < 23) {
            #pragma unroll
            for (int i = 0; i < 4; ++i) {
                gload16(sP[i] + (size_t)(t + 1) * 64 * CI, nb + dP[i]);
                gload16(sG[i] + (size_t)(t + 1) * 64, nb + dG[i]);
            }
        } else {
            // tail chunk (32 keys @ m0=1536): clamp sources; never-read slots get duplicates
            #pragma unroll
            for (int i = 0; i < 4; ++i) {
                int s16 = (k0 + i) * 64 + ln;
                int row = s16 >> 4, sl = s16 & 15;
                gload16(phib + (size_t)(1536 + (row & 31)) * CI + ((sl ^ (row & 15)) << 3), nb + dP[i]);
                int row2 = s16 >> 3, sl2 = s16 & 7;
                gload16(gb + (size_t)row2 * MM + 1536 + (((sl2 ^ (row2 & 7)) & 3) << 3), nb + dG[i]);
            }
        }
        const f16* cb = SB[t & 1];
        attn_chunk<2>(cb, cb + 8192, bth, yv, mrun, lrun, lq, hi);
        __syncthreads();    // drains vmcnt(0) -> next buffer ready
    }
    attn_chunk<1>(SB[0], SB[0] + 8192, bth, yv, mrun, lrun, lq, hi);

    // epilogue: y[n][ci] = yv/lrun
    float inv = 1.f / lrun;
    f16* yb = y + ((size_t)b * NN + n0 + wv * 32 + lq) * CI;
    #pragma unroll
    for (int c = 0; c < 4; ++c)
        #pragma unroll
        for (int k = 0; k < 4; ++k) {
            int ci = c * 32 + k * 8 + hi * 4;
            uint2 st;
            st.x = pkrtz(yv[c][4 * k + 0] * inv, yv[c][4 * k + 1] * inv);
            st.y = pkrtz(yv[c][4 * k + 2] * inv, yv[c][4 * k + 3] * inv);
            *(uint2*)(yb + ci) = st;
        }
}

// ---------------- K4: out = BN(wW @ y^T) + x ----------------
__global__ __launch_bounds__(256) void k_out(const f16* __restrict__ wWh, const f16* __restrict__ y,
                                             const float* __restrict__ x, const float* __restrict__ sc,
                                             const float* __restrict__ ofb, float* __restrict__ out) {
    int bid = blockIdx.x;                 // BB*196*2
    int b = bid / (196 * 2); int rem = bid % (196 * 2);
    int nt = rem >> 1, ct = rem & 1;
    int n0 = nt * 64, co0 = ct * 128;
    __shared__ f16 Ws[128 * 128];         // [co][ci] swizzled
    __shared__ f16 Ys[64 * 128];          // [n][ci] swizzled
    for (int s = threadIdx.x; s < 128 * 16; s += 256) {
        int row = s >> 4, sl = s & 15;
        f16x8 v = *(const f16x8*)(wWh + (size_t)(co0 + row) * CI + sl * 8);
        *(f16x8*)(Ws + row * 128 + ((sl * 8) ^ ((row & 7) << 3))) = v;
    }
    const f16* yb = y + (size_t)b * NN * CI + (size_t)n0 * CI;
    for (int s = threadIdx.x; s < 64 * 16; s += 256) {
        int row = s >> 4, sl = s & 15;
        f16x8 v = *(const f16x8*)(yb + (size_t)row * CI + sl * 8);
        *(f16x8*)(Ys + row * 128 + ((sl * 8) ^ ((row & 7) << 3))) = v;
    }
    __syncthreads();
    int wv = threadIdx.x >> 6, ln = threadIdx.x & 63;
    int wc = (wv >> 1) * 64, wn = (wv & 1) * 32;
    f32x4 acc[4][2];
    for (int i = 0; i < 4; ++i) for (int j = 0; j < 2; ++j)
        for (int r = 0; r < 4; ++r) acc[i][j][r] = 0.f;
    for (int kc = 0; kc < 4; ++kc) {
        int klo = kc * 32 + (ln >> 4) * 8;
        f16x8 afr[4], bfr[2];
        for (int i = 0; i < 4; ++i) {
            int rc = wc + i * 16 + (ln & 15);
            afr[i] = *(const f16x8*)(Ws + rc * 128 + (klo ^ ((rc & 7) << 3)));
        }
        for (int j = 0; j < 2; ++j) {
            int rn = wn + j * 16 + (ln & 15);
            bfr[j] = *(const f16x8*)(Ys + rn * 128 + (klo ^ ((rn & 7) << 3)));
        }
        for (int i = 0; i < 4; ++i)
            for (int j = 0; j < 2; ++j)
                acc[i][j] = mfma16(afr[i], bfr[j], acc[i][j]);
    }
    const float* xb = x + (size_t)b * CC * NN;
    float* ob = out + (size_t)b * CC * NN;
    for (int i = 0; i < 4; ++i)
        for (int j = 0; j < 2; ++j)
            for (int r = 0; r < 4; ++r) {
                int co = co0 + wc + i * 16 + (ln >> 4) * 4 + r;
                int n = n0 + wn + j * 16 + (ln & 15);
                size_t idx = (size_t)co * NN + n;
                ob[idx] = acc[i][j][r] * sc[co] + ofb[co] + xb[idx];
            }
}

extern "C" void kernel_launch(void* const* d_in, const int* in_sizes, int n_in,
                              void* d_out, int out_size, void* d_ws, size_t ws_size,
                              hipStream_t stream) {
    const float* x    = (const float*)d_in[0];
    const float* wg   = (const float*)d_in[1];
    const float* bg   = (const float*)d_in[2];
    const float* wth  = (const float*)d_in[3];
    const float* bth  = (const float*)d_in[4];
    const float* wph  = (const float*)d_in[5];
    const float* bph  = (const float*)d_in[6];
    const float* wW   = (const float*)d_in[7];
    const float* bW   = (const float*)d_in[8];
    const float* gam  = (const float*)d_in[9];
    const float* bet  = (const float*)d_in[10];
    const float* mean = (const float*)d_in[11];
    const float* var  = (const float*)d_in[12];
    if (ws_size < (size_t)WS_NEED) return;
    char* ws = (char*)d_ws;
    f16* w3t = (f16*)(ws + OFF_W3T);
    f16* wWh = (f16*)(ws + OFF_WWH);
    f16* b3  = (f16*)(ws + OFF_B3);
    float* sc  = (float*)(ws + OFF_SC);
    float* ofb = (float*)(ws + OFF_OFB);
    f16* xT  = (f16*)(ws + OFF_XT);
    f16* tpg = (f16*)(ws + OFF_TPG);
    f16* phi = (f16*)(ws + OFF_PHI);
    f16* gx  = (f16*)(ws + OFF_G);
    f16* yy  = (f16*)(ws + OFF_Y);
    float* out = (float*)d_out;

    k_prep<<<dim3(384), dim3(256), 0, stream>>>(wg, bg, wth, bth, wph, bph, wW, bW,
                                                gam, bet, mean, var, w3t, wWh, b3, sc, ofb);
    k_xt  <<<dim3(BB * 196 * 4), dim3(256), 0, stream>>>(x, xT);
    k_conv<<<dim3(BB * 98 * 3), dim3(256), 0, stream>>>(xT, w3t, b3, tpg);
    k_pool<<<dim3(BB * TP * HP), dim3(256), 0, stream>>>(tpg, phi, gx);
    k_attn<<<dim3(BB * 98), dim3(256), 0, stream>>>(tpg, phi, gx, yy);
    k_out <<<dim3(BB * 196 * 2), dim3(256), 0, stream>>>(wWh, yy, x, sc, ofb, out);
}